// Round 1
// baseline (150.280 us; speedup 1.0000x reference)
//
#include <hip/hip_runtime.h>

typedef __attribute__((ext_vector_type(8))) short bf16x8;
typedef __attribute__((ext_vector_type(4))) float f32x4;
typedef unsigned int u32;
typedef unsigned short u16;

#define NROWS 8192
#define NDIM 128
#define NSPLIT 16
#define COLS_PER_SPLIT (NROWS / NSPLIT) /* 512 */
#define BN 64
#define ITERS (COLS_PER_SPLIT / BN) /* 8 */

// ---------------- convert fp32 -> bf16 (+ fused pt_loss partial) ----------------

__device__ __forceinline__ u16 f2bf(float x) {
  u32 u = __float_as_uint(x);
  u32 r = (u + 0x7fffu + ((u >> 16) & 1u)) >> 16; // RTNE
  return (u16)r;
}

__global__ __launch_bounds__(256) void esupcon_convert(
    const float* __restrict__ za, const float* __restrict__ zt,
    const float* __restrict__ w, u16* __restrict__ zabf,
    u16* __restrict__ ztbf, float* __restrict__ pt_part) {
  const int b = blockIdx.x, t = threadIdx.x;
  const bool tp = b >= 1024;
  const float* src = tp ? zt : za;
  u16* dst = tp ? ztbf : zabf;
  const int base = ((b & 1023) * 256 + t) * 4;
  float4 v = *reinterpret_cast<const float4*>(src + base);
  ushort4 o;
  o.x = f2bf(v.x); o.y = f2bf(v.y); o.z = f2bf(v.z); o.w = f2bf(v.w);
  *reinterpret_cast<ushort4*>(dst + base) = o;

  const int k = base & (NDIM - 1); // 4 consecutive k, no row crossing
  float p = v.x * (w[NDIM + k + 0] - w[k + 0]) + v.y * (w[NDIM + k + 1] - w[k + 1]) +
            v.z * (w[NDIM + k + 2] - w[k + 2]) + v.w * (w[NDIM + k + 3] - w[k + 3]);
  if (tp) p = -p;

  __shared__ float red[256];
  red[t] = p;
  __syncthreads();
  for (int st = 128; st > 0; st >>= 1) {
    if (t < st) red[t] += red[t + st];
    __syncthreads();
  }
  if (t == 0) pt_part[b] = red[0];
}

// ---------------- stage 1: 3 GEMMs with exp+rowsum epilogue ----------------

template <bool MASK>
__device__ __forceinline__ void epilogue(const f32x4 (&acc)[3][2][2],
                                         float (&poss)[2][4], float (&negs)[2][4],
                                         float* __restrict__ diagv, int wrow0,
                                         int colw0, int lane) {
#pragma unroll
  for (int rt = 0; rt < 2; ++rt)
#pragma unroll
    for (int ct = 0; ct < 2; ++ct) {
      const int col_g = colw0 + ct * 16 + (lane & 15);
      const int rbase = wrow0 + rt * 16 + ((lane >> 4) << 2);
#pragma unroll
      for (int r = 0; r < 4; ++r) {
        float eaa = __expf(acc[0][rt][ct][r]);
        float ett = __expf(acc[1][rt][ct][r]);
        float vat = acc[2][rt][ct][r];
        float eat = __expf(vat);
        float ppos = eaa + ett;
        if (MASK) {
          const bool dia = (rbase + r) == col_g;
          if (dia) {
            diagv[rbase + r] = vat;
            ppos = 0.f;
            eat = 0.f;
          }
        }
        poss[rt][r] += ppos;
        negs[rt][r] += eat;
      }
    }
}

__global__ __launch_bounds__(256) void esupcon_stage1(
    const u16* __restrict__ zabf, const u16* __restrict__ ztbf,
    float* __restrict__ pos_part, float* __restrict__ neg_part,
    float* __restrict__ diagv) {
  __shared__ char ldsA[16384]; // 64 cols x 128 k bf16, st-swizzled
  __shared__ char ldsT[16384];

  const int tid = threadIdx.x;
  const int lane = tid & 63;
  const int wid = tid >> 6;
  const int wr = wid >> 1, wc = wid & 1;
  const int by = blockIdx.y; // row tile (64 rows)
  const int bx = blockIdx.x; // column split
  const int wrow0 = by * 64 + wr * 32;

  // A fragments (rows of z_au / z_tp) live in registers: [mat][rt][kstep]
  bf16x8 afrag[2][2][4];
  {
    const int rlo = lane & 15, kg = lane >> 4;
#pragma unroll
    for (int rt = 0; rt < 2; ++rt) {
      const u16* pa = zabf + (size_t)(wrow0 + rt * 16 + rlo) * NDIM + kg * 8;
      const u16* pt = ztbf + (size_t)(wrow0 + rt * 16 + rlo) * NDIM + kg * 8;
#pragma unroll
      for (int s = 0; s < 4; ++s) {
        afrag[0][rt][s] = *reinterpret_cast<const bf16x8*>(pa + s * 32);
        afrag[1][rt][s] = *reinterpret_cast<const bf16x8*>(pt + s * 32);
      }
    }
  }

  float poss[2][4], negs[2][4];
#pragma unroll
  for (int rt = 0; rt < 2; ++rt)
#pragma unroll
    for (int r = 0; r < 4; ++r) {
      poss[rt][r] = 0.f;
      negs[rt][r] = 0.f;
    }

  for (int it = 0; it < ITERS; ++it) {
    const int col0g = bx * COLS_PER_SPLIT + it * BN;
    __syncthreads(); // previous iteration's ds_reads done before overwrite
    {
      const char* gA = (const char*)(zabf + (size_t)col0g * NDIM);
      const char* gT = (const char*)(ztbf + (size_t)col0g * NDIM);
#pragma unroll
      for (int i = 0; i < 4; ++i) {
        const int chunk = wid * 4 + i;
        const int y = chunk * 1024 + lane * 16;
        const int ysw = y ^ (((y >> 8) & 7) << 4); // involutive st-swizzle
        __builtin_amdgcn_global_load_lds(
            (const __attribute__((address_space(1))) u32*)(gA + ysw),
            (__attribute__((address_space(3))) u32*)(ldsA + chunk * 1024), 16, 0, 0);
        __builtin_amdgcn_global_load_lds(
            (const __attribute__((address_space(1))) u32*)(gT + ysw),
            (__attribute__((address_space(3))) u32*)(ldsT + chunk * 1024), 16, 0, 0);
      }
    }
    __syncthreads(); // staging complete (barrier drains vmcnt)

    f32x4 acc[3][2][2] = {}; // [aa,tt,at][rt][ct]
#pragma unroll
    for (int s = 0; s < 4; ++s) {
      bf16x8 bA[2], bT[2];
#pragma unroll
      for (int ct = 0; ct < 2; ++ct) {
        const int c = wc * 32 + ct * 16 + (lane & 15);
        const int off = (c * 256 + s * 64 + (lane >> 4) * 16) ^ ((c & 7) << 4);
        bA[ct] = *reinterpret_cast<const bf16x8*>(ldsA + off);
        bT[ct] = *reinterpret_cast<const bf16x8*>(ldsT + off);
      }
#pragma unroll
      for (int rt = 0; rt < 2; ++rt)
#pragma unroll
        for (int ct = 0; ct < 2; ++ct) {
          acc[0][rt][ct] = __builtin_amdgcn_mfma_f32_16x16x32_bf16(
              afrag[0][rt][s], bA[ct], acc[0][rt][ct], 0, 0, 0);
          acc[1][rt][ct] = __builtin_amdgcn_mfma_f32_16x16x32_bf16(
              afrag[1][rt][s], bT[ct], acc[1][rt][ct], 0, 0, 0);
          acc[2][rt][ct] = __builtin_amdgcn_mfma_f32_16x16x32_bf16(
              afrag[0][rt][s], bT[ct], acc[2][rt][ct], 0, 0, 0);
        }
    }

    const bool hasdiag = (col0g == by * 64); // wave-uniform
    if (hasdiag)
      epilogue<true>(acc, poss, negs, diagv, wrow0, col0g + wc * 32, lane);
    else
      epilogue<false>(acc, poss, negs, diagv, wrow0, col0g + wc * 32, lane);
  }

  // reduce across the 16 lanes that share each row set
#pragma unroll
  for (int m = 1; m < 16; m <<= 1) {
#pragma unroll
    for (int rt = 0; rt < 2; ++rt)
#pragma unroll
      for (int r = 0; r < 4; ++r) {
        poss[rt][r] += __shfl_xor(poss[rt][r], m, 64);
        negs[rt][r] += __shfl_xor(negs[rt][r], m, 64);
      }
  }

  if ((lane & 15) == 0) {
    const int sp = bx * 2 + wc; // 32 partial slots per row
#pragma unroll
    for (int rt = 0; rt < 2; ++rt) {
      const int rbase = wrow0 + rt * 16 + ((lane >> 4) << 2);
#pragma unroll
      for (int r = 0; r < 4; ++r) {
        pos_part[(size_t)(rbase + r) * 32 + sp] = poss[rt][r];
        neg_part[(size_t)(rbase + r) * 32 + sp] = negs[rt][r];
      }
    }
  }
}

// ---------------- final deterministic reduction ----------------

__global__ __launch_bounds__(256) void esupcon_reduce(
    const float* __restrict__ pos_part, const float* __restrict__ neg_part,
    const float* __restrict__ diagv, const float* __restrict__ pt_part,
    float* __restrict__ out) {
  const int t = threadIdx.x;
  float sc = 0.f;
  for (int r = t; r < NROWS; r += 256) {
    float P = 0.f, Nn = 0.f;
#pragma unroll
    for (int s = 0; s < 32; ++s) {
      P += pos_part[(size_t)r * 32 + s];
      Nn += neg_part[(size_t)r * 32 + s];
    }
    sc += -logf(P) + logf(Nn) + 2.0f * diagv[r];
  }
  float pp = 0.f;
  for (int i = t; i < 2048; i += 256) pp += pt_part[i];

  __shared__ float s1[256], s2[256];
  s1[t] = sc;
  s2[t] = pp;
  __syncthreads();
  for (int st = 128; st > 0; st >>= 1) {
    if (t < st) {
      s1[t] += s1[t + st];
      s2[t] += s2[t + st];
    }
    __syncthreads();
  }
  if (t == 0) {
    const float pt_loss = s2[0] / (float)NROWS;
    out[0] = ((float)NROWS * (float)NDIM / ((float)NROWS + 2.0f)) * (pt_loss + s1[0]);
  }
}

// ---------------- launcher ----------------

extern "C" void kernel_launch(void* const* d_in, const int* in_sizes, int n_in,
                              void* d_out, int out_size, void* d_ws, size_t ws_size,
                              hipStream_t stream) {
  const float* za = (const float*)d_in[0];
  const float* zt = (const float*)d_in[1];
  const float* w = (const float*)d_in[2];
  float* out = (float*)d_out;

  char* ws = (char*)d_ws;
  u16* zabf = (u16*)ws;                                    // 2 MB
  u16* ztbf = (u16*)(ws + (size_t)(1 << 21));              // 2 MB
  float* pos_part = (float*)(ws + (size_t)(2 << 21));      // 1 MB (8192*32)
  float* neg_part = (float*)(ws + (size_t)(2 << 21) + (1 << 20));
  float* diagv = (float*)(ws + (size_t)(2 << 21) + (2 << 20));             // 32 KB
  float* pt_part = (float*)(ws + (size_t)(2 << 21) + (2 << 20) + (1 << 15)); // 8 KB

  esupcon_convert<<<dim3(2048), dim3(256), 0, stream>>>(za, zt, w, zabf, ztbf, pt_part);
  esupcon_stage1<<<dim3(NSPLIT, NROWS / 64), dim3(256), 0, stream>>>(
      zabf, ztbf, pos_part, neg_part, diagv);
  esupcon_reduce<<<dim3(1), dim3(256), 0, stream>>>(pos_part, neg_part, diagv,
                                                    pt_part, out);
}

// Round 2
// 80.086 us; speedup vs baseline: 1.8765x; 1.8765x over previous
//
#include <hip/hip_runtime.h>

typedef __attribute__((ext_vector_type(8))) short bf16x8;
typedef __attribute__((ext_vector_type(4))) float f32x4;
typedef unsigned int u32;
typedef unsigned short u16;

#define NROWS 8192
#define NDIM 128
#define NSPLIT 16
#define COLS_PER_SPLIT (NROWS / NSPLIT) /* 512 */
#define BN 64
#define ITERS (COLS_PER_SPLIT / BN) /* 8 */

#define SQRT_LOG2E 1.2011224087864498f /* sqrt(log2(e)); S_scaled = S*log2e */
#define TWO_OVER_LOG2E 1.3862943611198906f /* 2/log2(e) */

__device__ __forceinline__ float hw_exp2(float x) {
  float r;
  asm("v_exp_f32 %0, %1" : "=v"(r) : "v"(x));
  return r;
}

// ---------------- convert fp32 -> bf16*sqrt(log2e) (+ fused pt_loss partial) --

__device__ __forceinline__ u16 f2bf(float x) {
  u32 u = __float_as_uint(x);
  u32 r = (u + 0x7fffu + ((u >> 16) & 1u)) >> 16; // RTNE
  return (u16)r;
}

__global__ __launch_bounds__(256) void esupcon_convert(
    const float* __restrict__ za, const float* __restrict__ zt,
    const float* __restrict__ w, u16* __restrict__ zabf,
    u16* __restrict__ ztbf, float* __restrict__ pt_part) {
  const int b = blockIdx.x, t = threadIdx.x;
  const bool tp = b >= 1024;
  const float* src = tp ? zt : za;
  u16* dst = tp ? ztbf : zabf;
  const int base = ((b & 1023) * 256 + t) * 4;
  float4 v = *reinterpret_cast<const float4*>(src + base);

  // pt partial from UNSCALED values
  const int k = base & (NDIM - 1); // 4 consecutive k, no row crossing
  float p = v.x * (w[NDIM + k + 0] - w[k + 0]) + v.y * (w[NDIM + k + 1] - w[k + 1]) +
            v.z * (w[NDIM + k + 2] - w[k + 2]) + v.w * (w[NDIM + k + 3] - w[k + 3]);
  if (tp) p = -p;

  ushort4 o;
  o.x = f2bf(v.x * SQRT_LOG2E);
  o.y = f2bf(v.y * SQRT_LOG2E);
  o.z = f2bf(v.z * SQRT_LOG2E);
  o.w = f2bf(v.w * SQRT_LOG2E);
  *reinterpret_cast<ushort4*>(dst + base) = o;

  __shared__ float red[256];
  red[t] = p;
  __syncthreads();
  for (int st = 128; st > 0; st >>= 1) {
    if (t < st) red[t] += red[t + st];
    __syncthreads();
  }
  if (t == 0) pt_part[b] = red[0];
}

// ---------------- stage 1: 3 GEMMs with exp+rowsum epilogue ----------------

template <bool MASK>
__device__ __forceinline__ void epilogue(const f32x4 (&acc)[3][2][2],
                                         float (&poss)[2][4], float (&negs)[2][4],
                                         float* __restrict__ diagv, int wrow0,
                                         int colw0, int lane) {
#pragma unroll
  for (int rt = 0; rt < 2; ++rt)
#pragma unroll
    for (int ct = 0; ct < 2; ++ct) {
      const int col_g = colw0 + ct * 16 + (lane & 15);
      const int rbase = wrow0 + rt * 16 + ((lane >> 4) << 2);
#pragma unroll
      for (int r = 0; r < 4; ++r) {
        // acc values are S*log2e -> exp2(acc) == exp(S)
        float eaa = hw_exp2(acc[0][rt][ct][r]);
        float ett = hw_exp2(acc[1][rt][ct][r]);
        float vat = acc[2][rt][ct][r];
        float eat = hw_exp2(vat);
        float ppos = eaa + ett;
        if (MASK) {
          const bool dia = (rbase + r) == col_g;
          if (dia) {
            diagv[rbase + r] = vat; // scaled by log2e; fixed in reduce1
            ppos = 0.f;
            eat = 0.f;
          }
        }
        poss[rt][r] += ppos;
        negs[rt][r] += eat;
      }
    }
}

__global__ __launch_bounds__(256, 2) void esupcon_stage1(
    const u16* __restrict__ zabf, const u16* __restrict__ ztbf,
    float* __restrict__ pos_part, float* __restrict__ neg_part,
    float* __restrict__ diagv) {
  // double-buffered: [buf][ A 16KB | T 16KB ]
  __shared__ __align__(16) char lds[2][32768];

  const int tid = threadIdx.x;
  const int lane = tid & 63;
  const int wid = tid >> 6;
  const int wr = wid >> 1, wc = wid & 1;
  const int by = blockIdx.x; // row tile (64 rows) -- consecutive blocks share cols
  const int bx = blockIdx.y; // column split
  const int wrow0 = by * 64 + wr * 32;

  // A fragments (rows of z_au / z_tp) live in registers: [mat][rt][kstep]
  bf16x8 afrag[2][2][4];
  {
    const int rlo = lane & 15, kg = lane >> 4;
#pragma unroll
    for (int rt = 0; rt < 2; ++rt) {
      const u16* pa = zabf + (size_t)(wrow0 + rt * 16 + rlo) * NDIM + kg * 8;
      const u16* pt = ztbf + (size_t)(wrow0 + rt * 16 + rlo) * NDIM + kg * 8;
#pragma unroll
      for (int s = 0; s < 4; ++s) {
        afrag[0][rt][s] = *reinterpret_cast<const bf16x8*>(pa + s * 32);
        afrag[1][rt][s] = *reinterpret_cast<const bf16x8*>(pt + s * 32);
      }
    }
  }

  float poss[2][4], negs[2][4];
#pragma unroll
  for (int rt = 0; rt < 2; ++rt)
#pragma unroll
    for (int r = 0; r < 4; ++r) {
      poss[rt][r] = 0.f;
      negs[rt][r] = 0.f;
    }

  // async staging of one 64-col tile (both matrices) into lds[buf]
  auto stage = [&](int buf, int it) {
    const int col0g = bx * COLS_PER_SPLIT + it * BN;
    const char* gA = (const char*)(zabf + (size_t)col0g * NDIM);
    const char* gT = (const char*)(ztbf + (size_t)col0g * NDIM);
    char* lA = &lds[buf][0];
    char* lT = &lds[buf][16384];
#pragma unroll
    for (int i = 0; i < 4; ++i) {
      const int chunk = wid * 4 + i;
      const int y = chunk * 1024 + lane * 16;
      const int ysw = y ^ (((y >> 8) & 7) << 4); // involutive st-swizzle
      __builtin_amdgcn_global_load_lds(
          (const __attribute__((address_space(1))) u32*)(gA + ysw),
          (__attribute__((address_space(3))) u32*)(lA + chunk * 1024), 16, 0, 0);
      __builtin_amdgcn_global_load_lds(
          (const __attribute__((address_space(1))) u32*)(gT + ysw),
          (__attribute__((address_space(3))) u32*)(lT + chunk * 1024), 16, 0, 0);
    }
  };

  int cur = 0;
  stage(0, 0);

  for (int it = 0; it < ITERS; ++it) {
    // own prefetch landed; all waves done reading the other buffer
    asm volatile("s_waitcnt vmcnt(0)" ::: "memory");
    __builtin_amdgcn_s_barrier();
    asm volatile("" ::: "memory");

    if (it + 1 < ITERS) stage(cur ^ 1, it + 1); // async, flies under compute

    const char* lA = &lds[cur][0];
    const char* lT = &lds[cur][16384];

    f32x4 acc[3][2][2] = {}; // [aa,tt,at][rt][ct]
#pragma unroll
    for (int s = 0; s < 4; ++s) {
      bf16x8 bA[2], bT[2];
#pragma unroll
      for (int ct = 0; ct < 2; ++ct) {
        const int c = wc * 32 + ct * 16 + (lane & 15);
        const int off = (c * 256 + s * 64 + (lane >> 4) * 16) ^ ((c & 7) << 4);
        bA[ct] = *reinterpret_cast<const bf16x8*>(lA + off);
        bT[ct] = *reinterpret_cast<const bf16x8*>(lT + off);
      }
#pragma unroll
      for (int rt = 0; rt < 2; ++rt)
#pragma unroll
        for (int ct = 0; ct < 2; ++ct) {
          acc[0][rt][ct] = __builtin_amdgcn_mfma_f32_16x16x32_bf16(
              afrag[0][rt][s], bA[ct], acc[0][rt][ct], 0, 0, 0);
          acc[1][rt][ct] = __builtin_amdgcn_mfma_f32_16x16x32_bf16(
              afrag[1][rt][s], bT[ct], acc[1][rt][ct], 0, 0, 0);
          acc[2][rt][ct] = __builtin_amdgcn_mfma_f32_16x16x32_bf16(
              afrag[0][rt][s], bT[ct], acc[2][rt][ct], 0, 0, 0);
        }
    }

    const int col0g = bx * COLS_PER_SPLIT + it * BN;
    const bool hasdiag = (col0g == by * 64); // wave-uniform
    if (hasdiag)
      epilogue<true>(acc, poss, negs, diagv, wrow0, col0g + wc * 32, lane);
    else
      epilogue<false>(acc, poss, negs, diagv, wrow0, col0g + wc * 32, lane);

    cur ^= 1;
  }

  // reduce across the 16 lanes that share each row set
#pragma unroll
  for (int m = 1; m < 16; m <<= 1) {
#pragma unroll
    for (int rt = 0; rt < 2; ++rt)
#pragma unroll
      for (int r = 0; r < 4; ++r) {
        poss[rt][r] += __shfl_xor(poss[rt][r], m, 64);
        negs[rt][r] += __shfl_xor(negs[rt][r], m, 64);
      }
  }

  if ((lane & 15) == 0) {
    const int sp = bx * 2 + wc; // 32 partial slots per row
#pragma unroll
    for (int rt = 0; rt < 2; ++rt) {
      const int rbase = wrow0 + rt * 16 + ((lane >> 4) << 2);
#pragma unroll
      for (int r = 0; r < 4; ++r) {
        pos_part[(size_t)(rbase + r) * 32 + sp] = poss[rt][r];
        neg_part[(size_t)(rbase + r) * 32 + sp] = negs[rt][r];
      }
    }
  }
}

// ---------------- parallel reduction, stage A: 32 blocks ----------------

__global__ __launch_bounds__(256) void esupcon_reduce1(
    const float* __restrict__ pos_part, const float* __restrict__ neg_part,
    const float* __restrict__ diagv, const float* __restrict__ pt_part,
    float* __restrict__ part_out /* [64]: 0..31 supcon, 32..63 pt */) {
  const int b = blockIdx.x, t = threadIdx.x;
  const int r = b * 256 + t; // one row per thread
  const f32x4* pp = reinterpret_cast<const f32x4*>(pos_part + (size_t)r * 32);
  const f32x4* np = reinterpret_cast<const f32x4*>(neg_part + (size_t)r * 32);
  float P = 0.f, Nn = 0.f;
#pragma unroll
  for (int s = 0; s < 8; ++s) {
    f32x4 a = pp[s], c = np[s];
    P += a[0] + a[1] + a[2] + a[3];
    Nn += c[0] + c[1] + c[2] + c[3];
  }
  float sc = -logf(P) + logf(Nn) + TWO_OVER_LOG2E * diagv[r];
  float pt = (t < 64) ? pt_part[b * 64 + t] : 0.f;

  __shared__ float s1[256], s2[256];
  s1[t] = sc;
  s2[t] = pt;
  __syncthreads();
  for (int st = 128; st > 0; st >>= 1) {
    if (t < st) {
      s1[t] += s1[t + st];
      s2[t] += s2[t + st];
    }
    __syncthreads();
  }
  if (t == 0) {
    part_out[b] = s1[0];
    part_out[32 + b] = s2[0];
  }
}

// ---------------- final reduction: 1 block, 1 wave ----------------

__global__ __launch_bounds__(64) void esupcon_reduce2(
    const float* __restrict__ part_out, float* __restrict__ out) {
  const int t = threadIdx.x;
  float sc = (t < 32) ? part_out[t] : 0.f;
  float pt = (t < 32) ? part_out[32 + t] : 0.f;
#pragma unroll
  for (int m = 1; m < 64; m <<= 1) {
    sc += __shfl_xor(sc, m, 64);
    pt += __shfl_xor(pt, m, 64);
  }
  if (t == 0) {
    const float pt_loss = pt / (float)NROWS;
    out[0] = ((float)NROWS * (float)NDIM / ((float)NROWS + 2.0f)) * (pt_loss + sc);
  }
}

// ---------------- launcher ----------------

extern "C" void kernel_launch(void* const* d_in, const int* in_sizes, int n_in,
                              void* d_out, int out_size, void* d_ws, size_t ws_size,
                              hipStream_t stream) {
  const float* za = (const float*)d_in[0];
  const float* zt = (const float*)d_in[1];
  const float* w = (const float*)d_in[2];
  float* out = (float*)d_out;

  char* ws = (char*)d_ws;
  u16* zabf = (u16*)ws;                                    // 2 MB
  u16* ztbf = (u16*)(ws + (size_t)(1 << 21));              // 2 MB
  float* pos_part = (float*)(ws + (size_t)(2 << 21));      // 1 MB (8192*32)
  float* neg_part = (float*)(ws + (size_t)(2 << 21) + (1 << 20));
  float* diagv = (float*)(ws + (size_t)(2 << 21) + (2 << 20));               // 32 KB
  float* pt_part = (float*)(ws + (size_t)(2 << 21) + (2 << 20) + (1 << 15)); // 8 KB
  float* part_out = (float*)(ws + (size_t)(2 << 21) + (2 << 20) + (1 << 15) + (1 << 13));

  esupcon_convert<<<dim3(2048), dim3(256), 0, stream>>>(za, zt, w, zabf, ztbf, pt_part);
  esupcon_stage1<<<dim3(NROWS / 64, NSPLIT), dim3(256), 0, stream>>>(
      zabf, ztbf, pos_part, neg_part, diagv);
  esupcon_reduce1<<<dim3(32), dim3(256), 0, stream>>>(pos_part, neg_part, diagv,
                                                      pt_part, part_out);
  esupcon_reduce2<<<dim3(1), dim3(64), 0, stream>>>(part_out, out);
}